// Round 10
// baseline (130.389 us; speedup 1.0000x reference)
//
#include <hip/hip_runtime.h>
#include <hip/hip_fp16.h>

// Warp: trilinear grid_sample, padding_mode='zeros', align_corners=true.
// image: (B=2, C=1, H=128, W=128, D=128) fp32
// ddf:   (B=2, 3, H, W, D) fp32 voxel displacements; out: (B,1,H,W,D) fp32
//
// R9 post-mortem: lane-slot model failed (32 vs 48 slots -> same 36us).
// Residual = phase serialization: stage->barrier->compute alternation leaves
// HBM idle ~55% (R5 measured 1.9 of 6.3 TB/s). R10: 512 blocks (exactly
// 2/CU, one generation), each does a z-adjacent tile PAIR in one 64KB
// buffer; tile-B ddf + half of B staging issued before compute-A so B's
// global loads stream under A's compute. VGPR kept <=64 (launch_bounds
// (1024,8)) so 2 blocks/CU is preserved -- the R6 trap avoided.

constexpr int H = 128, W = 128, D = 128;
constexpr int N = H * W * D;      // 2^21
constexpr int B = 2;
constexpr int HA = 8;             // halo per side
constexpr int RS = 32;            // region edge
constexpr int RN = RS * RS * RS;  // 32768 fp16 = 64 KB

typedef float fvec4 __attribute__((ext_vector_type(4)));

__device__ __forceinline__ void stage_load(const float* __restrict__ img,
    int ox, int oy, int oz, int t, int c, fvec4& A, fvec4& Bv)
{
    int s   = c * 1024 + t;
    int row = s >> 2;             // rx*32 + ry
    int zo  = (s & 3) << 3;
    int gx = ox + (row >> 5);
    int gy = oy + (row & 31);
    int gz = oz + zo;             // oz ≡ 0 mod 8 -> chunk fully in or out
    bool ok = ((unsigned)gx < 128u) & ((unsigned)gy < 128u) & ((unsigned)gz < 121u);
    const float* p = img + (gx << 14) + (gy << 7) + gz;
    fvec4 z4 = {0.f, 0.f, 0.f, 0.f};
    A  = ok ? *(const fvec4*)p       : z4;
    Bv = ok ? *(const fvec4*)(p + 4) : z4;
}

__device__ __forceinline__ void stage_write(__half* __restrict__ tile,
    int t, int c, fvec4 A, fvec4 Bv)
{
    int s   = c * 1024 + t;
    int row = s >> 2;
    int zo  = (s & 3) << 3;
    __half2 h0 = __floats2half2_rn(A.x, A.y);
    __half2 h1 = __floats2half2_rn(A.z, A.w);
    __half2 h2 = __floats2half2_rn(Bv.x, Bv.y);
    __half2 h3 = __floats2half2_rn(Bv.z, Bv.w);
    uint4 pk;
    pk.x = *(unsigned int*)&h0;
    pk.y = *(unsigned int*)&h1;
    pk.z = *(unsigned int*)&h2;
    pk.w = *(unsigned int*)&h3;
    *(uint4*)((unsigned short*)tile + row * 32 + zo) = pk;  // ds_write_b128
}

__device__ __forceinline__ void compute_tile(const __half* __restrict__ tile,
    const float* __restrict__ img, float* __restrict__ outb,
    int vx, int vy, int vz, int lin0, int ox, int oy, int oz,
    fvec4 dx4, fvec4 dy4, fvec4 dz4)
{
    const unsigned int* cells = (const unsigned int*)tile;   // half2 cells
    float dxp[4] = {dx4.x, dx4.y, dx4.z, dx4.w};
    float dyp[4] = {dy4.x, dy4.y, dy4.z, dy4.w};
    float dzp[4] = {dz4.x, dz4.y, dz4.z, dz4.w};
    float res[4];

#pragma unroll
    for (int i = 0; i < 4; ++i) {
        float x = (float)vx + dxp[i];
        float y = (float)vy + dyp[i];
        float z = (float)(vz + i) + dzp[i];

        float xf = floorf(x), yf = floorf(y), zf = floorf(z);
        float fx = x - xf, fy = y - yf, fz = z - zf;
        int x0 = (int)xf, y0 = (int)yf, z0 = (int)zf;
        int rx = x0 - ox, ry = y0 - oy, rz = z0 - oz;

        float acc;
        if ((unsigned)rx <= 30u && (unsigned)ry <= 30u && (unsigned)rz <= 30u) {
            // fast path: staged zeros implement zero-padding exactly.
            int rowc = ((rx << 5) + ry) << 4;   // row * 16 cells
            int c  = rowc + (rz >> 1);
            int sh = (rz & 1) << 4;
            unsigned los[4] = {cells[c],       cells[c + 16],
                               cells[c + 512], cells[c + 528]};
            unsigned his[4] = {cells[c + 1],   cells[c + 17],
                               cells[c + 513], cells[c + 529]};
            float az0 = 1.f - fz;
            float zz[4];
#pragma unroll
            for (int p2 = 0; p2 < 4; ++p2) {
                unsigned long long v = ((unsigned long long)his[p2] << 32) | los[p2];
                unsigned pr = (unsigned)(v >> sh);
                __half2 hp = *(__half2*)&pr;
                float2 f2 = __half22float2(hp);
                zz[p2] = az0 * f2.x + fz * f2.y;
            }
            float ay0 = 1.f - fy;
            acc = (1.f - fx) * (ay0 * zz[0] + fy * zz[1]) +
                  fx         * (ay0 * zz[2] + fy * zz[3]);
        } else {
            // rare: exact fp32 global gather with zero-padding.
            int x1 = x0 + 1, y1 = y0 + 1, z1 = z0 + 1;
            bool vx0 = (unsigned)x0 < (unsigned)H;
            bool vx1 = (unsigned)x1 < (unsigned)H;
            bool vy0 = (unsigned)y0 < (unsigned)W;
            bool vy1 = (unsigned)y1 < (unsigned)W;
            bool vz0 = (unsigned)z0 < (unsigned)D;
            bool vz1 = (unsigned)z1 < (unsigned)D;
            float ax0 = vx0 ? (1.0f - fx) : 0.0f;
            float ax1 = vx1 ? fx          : 0.0f;
            float ay0 = vy0 ? (1.0f - fy) : 0.0f;
            float ay1 = vy1 ? fy          : 0.0f;
            float az0 = vz0 ? (1.0f - fz) : 0.0f;
            float az1 = vz1 ? fz          : 0.0f;
            int cx0 = vx0 ? x0 : 0;
            int cx1 = vx1 ? x1 : 0;
            int cy0 = vy0 ? y0 : 0;
            int cy1 = vy1 ? y1 : 0;
            int cz0 = vz0 ? z0 : 0;
            int cz1 = vz1 ? z1 : 0;
            int rx0 = cx0 << 14, rx1 = cx1 << 14;
            int ry0 = cy0 << 7,  ry1 = cy1 << 7;
            float v000 = img[rx0 + ry0 + cz0];
            float v001 = img[rx0 + ry0 + cz1];
            float v010 = img[rx0 + ry1 + cz0];
            float v011 = img[rx0 + ry1 + cz1];
            float v100 = img[rx1 + ry0 + cz0];
            float v101 = img[rx1 + ry0 + cz1];
            float v110 = img[rx1 + ry1 + cz0];
            float v111 = img[rx1 + ry1 + cz1];
            acc = ax0 * (ay0 * (az0 * v000 + az1 * v001) +
                         ay1 * (az0 * v010 + az1 * v011)) +
                  ax1 * (ay0 * (az0 * v100 + az1 * v101) +
                         ay1 * (az0 * v110 + az1 * v111));
        }
        res[i] = acc;
    }
    fvec4 r4 = {res[0], res[1], res[2], res[3]};
    __builtin_nontemporal_store(r4, (fvec4*)(outb + lin0));
}

__global__ __launch_bounds__(1024, 8) void warp_pair_kernel(
    const float* __restrict__ image,
    const float* __restrict__ ddf,
    float* __restrict__ out)
{
    __shared__ __half tile[RN];   // 64 KB -> 2 blocks/CU

    int bid = blockIdx.x;         // 512 blocks = 256 pairs/batch x 2 batches
    int b = bid >> 8;
    int p = bid & 255;
    int tx0 = ((p >> 5) & 7) << 4;
    int ty0 = ((p >> 2) & 7) << 4;
    int tzA = (p & 3) << 5;       // pair covers z in [tzA, tzA+32)
    int tzB = tzA + 16;
    int ox = tx0 - HA, oy = ty0 - HA;
    int ozA = tzA - HA, ozB = tzB - HA;

    const float* img  = image + ((size_t)b << 21);
    const float* ddfb = ddf + (size_t)b * 3 * N;
    float* outb = out + ((size_t)b << 21);
    int t = threadIdx.x;

    // thread -> 4 consecutive z voxels of each tile
    int zq = (t & 3) << 2;
    int ly = (t >> 2) & 15;
    int lx = t >> 6;
    int vx = tx0 + lx, vy = ty0 + ly;
    int vzA = tzA + zq, vzB = tzB + zq;
    int linA = (vx << 14) + (vy << 7) + vzA;
    int linB = linA + 16;

    // ---- tile A: ddf + full stage ----
    fvec4 adx = *(const fvec4*)(ddfb + linA);
    fvec4 ady = *(const fvec4*)(ddfb + linA + N);
    fvec4 adz = *(const fvec4*)(ddfb + linA + 2 * N);

    fvec4 s0, s1, s2, s3, u0, u1, u2, u3;
    stage_load(img, ox, oy, ozA, t, 0, s0, u0);
    stage_load(img, ox, oy, ozA, t, 1, s1, u1);
    stage_load(img, ox, oy, ozA, t, 2, s2, u2);
    stage_load(img, ox, oy, ozA, t, 3, s3, u3);
    stage_write(tile, t, 0, s0, u0);
    stage_write(tile, t, 1, s1, u1);
    stage_write(tile, t, 2, s2, u2);
    stage_write(tile, t, 3, s3, u3);

    // ---- tile B: ddf + first half of stage, in flight during compute-A ----
    fvec4 bdx = *(const fvec4*)(ddfb + linB);
    fvec4 bdy = *(const fvec4*)(ddfb + linB + N);
    fvec4 bdz = *(const fvec4*)(ddfb + linB + 2 * N);
    stage_load(img, ox, oy, ozB, t, 0, s0, u0);
    stage_load(img, ox, oy, ozB, t, 1, s1, u1);

    __syncthreads();
    compute_tile(tile, img, outb, vx, vy, vzA, linA, ox, oy, ozA, adx, ady, adz);

    // second half of B staging (50% L1 hits: regions overlap 32x32x16)
    stage_load(img, ox, oy, ozB, t, 2, s2, u2);
    stage_load(img, ox, oy, ozB, t, 3, s3, u3);

    __syncthreads();              // all waves done reading tile A
    stage_write(tile, t, 0, s0, u0);
    stage_write(tile, t, 1, s1, u1);
    stage_write(tile, t, 2, s2, u2);
    stage_write(tile, t, 3, s3, u3);
    __syncthreads();

    compute_tile(tile, img, outb, vx, vy, vzB, linB, ox, oy, ozB, bdx, bdy, bdz);
}

extern "C" void kernel_launch(void* const* d_in, const int* in_sizes, int n_in,
                              void* d_out, int out_size, void* d_ws, size_t ws_size,
                              hipStream_t stream) {
    const float* image = (const float*)d_in[0];
    const float* ddf   = (const float*)d_in[1];
    float* out = (float*)d_out;

    warp_pair_kernel<<<512, 1024, 0, stream>>>(image, ddf, out);
}

// Round 11
// 105.600 us; speedup vs baseline: 1.2347x; 1.2347x over previous
//
#include <hip/hip_runtime.h>
#include <hip/hip_fp16.h>

// Warp: trilinear grid_sample, padding_mode='zeros', align_corners=true.
// image: (B=2, C=1, H=128, W=128, D=128) fp32
// ddf:   (B=2, 3, H, W, D) fp32 voxel displacements; out: (B,1,H,W,D) fp32
//
// R10 post-mortem: VGPR prefetch pipelining defeated by compiler (VGPR=32);
// z-pairing killed halo sharing (FETCH 127MB); tap path has 3.4M conflict
// cycles. R11 = R9 (best, kernel ~36us) + (1) XCD slab swizzle: bid&7 ->
// contiguous x-slab so halo re-reads hit same-XCD L2 (slab ~2MB < 4MB L2);
// (2) taps as 4B-aligned uint2 -> ds_read2_b32, halving LDS tap instrs and
// conflict exposure.

constexpr int H = 128, W = 128, D = 128;
constexpr int N = H * W * D;      // 2^21
constexpr int B = 2;
constexpr int HA = 8;             // halo per side
constexpr int RS = 32;            // region edge
constexpr int RN = RS * RS * RS;  // 32768 fp16 = 64 KB

typedef float fvec4 __attribute__((ext_vector_type(4)));
typedef unsigned u2v __attribute__((ext_vector_type(2), aligned(4)));

__global__ __launch_bounds__(1024, 8) void warp_tile_kernel(
    const float* __restrict__ image,
    const float* __restrict__ ddf,
    float* __restrict__ out)
{
    __shared__ __half tile[RN];   // 64 KB -> 2 blocks/CU

    // XCD slab swizzle: blocks dispatch round-robin over 8 XCDs; give XCD k
    // the contiguous tile range [k*128, (k+1)*128) (= 2 x-slabs, ~2MB image
    // region + halos -> fits that XCD's 4MB L2).
    int bid = blockIdx.x;
    int T   = (bid & 7) * 128 + (bid >> 3);
    int b  = T >> 9;              // 512 tiles per batch
    int t3 = T & 511;
    int tx0 = ((t3 >> 6) & 7) << 4;
    int ty0 = ((t3 >> 3) & 7) << 4;
    int tz0 = (t3 & 7) << 4;
    int ox = tx0 - HA, oy = ty0 - HA, oz = tz0 - HA;

    const float* img = image + ((size_t)b << 21);
    int t = threadIdx.x;          // 0..1023

    // ---- thread -> 4 consecutive z voxels ----
    int zq = (t & 3) << 2;        // 0,4,8,12
    int ly = (t >> 2) & 15;
    int lx = t >> 6;
    int vx = tx0 + lx, vy = ty0 + ly, vz = tz0 + zq;
    int lin0 = (vx << 14) + (vy << 7) + vz;      // 16B aligned

    // ddf prefetch: 3 vector loads (issue before staging; used after barrier)
    const float* ddfb = ddf + (size_t)b * 3 * N;
    fvec4 dx4 = *(const fvec4*)(ddfb + lin0);
    fvec4 dy4 = *(const fvec4*)(ddfb + lin0 + N);
    fvec4 dz4 = *(const fvec4*)(ddfb + lin0 + 2 * N);

    // ---- stage 32^3 region as fp16 (zeros outside volume) ----
    // 4096 32-byte slots; slot s: row = s>>2 (rx*32+ry), zo = (s&3)*8.
    // oz ≡ 0 mod 8 -> each 8-float chunk is fully inside or fully outside.
    fvec4 sa[4], sb[4];
    int rows[4], zos[4];
#pragma unroll
    for (int c = 0; c < 4; ++c) {
        int s   = c * 1024 + t;
        int row = s >> 2;
        int zo  = (s & 3) << 3;
        rows[c] = row; zos[c] = zo;
        int gx = ox + (row >> 5);
        int gy = oy + (row & 31);
        int gz = oz + zo;
        bool ok = ((unsigned)gx < 128u) & ((unsigned)gy < 128u) & ((unsigned)gz < 121u);
        const float* p = img + (gx << 14) + (gy << 7) + gz;
        fvec4 z4 = {0.f, 0.f, 0.f, 0.f};
        sa[c] = ok ? *(const fvec4*)p       : z4;
        sb[c] = ok ? *(const fvec4*)(p + 4) : z4;
    }
    unsigned short* tp = (unsigned short*)tile;
#pragma unroll
    for (int c = 0; c < 4; ++c) {
        __half2 h0 = __floats2half2_rn(sa[c].x, sa[c].y);
        __half2 h1 = __floats2half2_rn(sa[c].z, sa[c].w);
        __half2 h2 = __floats2half2_rn(sb[c].x, sb[c].y);
        __half2 h3 = __floats2half2_rn(sb[c].z, sb[c].w);
        uint4 pk;
        pk.x = *(unsigned int*)&h0;
        pk.y = *(unsigned int*)&h1;
        pk.z = *(unsigned int*)&h2;
        pk.w = *(unsigned int*)&h3;
        *(uint4*)(tp + rows[c] * 32 + zos[c]) = pk;   // ds_write_b128
    }
    __syncthreads();

    // ---- compute 4 outputs (consecutive z), one float4 store ----
    float* outb = out + ((size_t)b << 21);
    const unsigned int* cells = (const unsigned int*)tile;   // half2 cells, 4B
    float dxp[4] = {dx4.x, dx4.y, dx4.z, dx4.w};
    float dyp[4] = {dy4.x, dy4.y, dy4.z, dy4.w};
    float dzp[4] = {dz4.x, dz4.y, dz4.z, dz4.w};
    float res[4];

#pragma unroll
    for (int i = 0; i < 4; ++i) {
        float x = (float)vx + dxp[i];
        float y = (float)vy + dyp[i];
        float z = (float)(vz + i) + dzp[i];

        float xf = floorf(x), yf = floorf(y), zf = floorf(z);
        float fx = x - xf, fy = y - yf, fz = z - zf;
        int x0 = (int)xf, y0 = (int)yf, z0 = (int)zf;
        int rx = x0 - ox, ry = y0 - oy, rz = z0 - oz;

        float acc;
        if ((unsigned)rx <= 30u && (unsigned)ry <= 30u && (unsigned)rz <= 30u) {
            // fast path: staged zeros implement zero-padding exactly.
            // z-pair (rz, rz+1) in cells c,c+1 (4B-aligned uint2 ->
            // ds_read2_b32; cross-row c+1 read is discarded when rz even).
            int rowc = ((rx << 5) + ry) << 4;   // row * 16 cells
            int c  = rowc + (rz >> 1);
            int sh = (rz & 1) << 4;
            u2v q00 = *(const u2v*)(cells + c);
            u2v q01 = *(const u2v*)(cells + c + 16);
            u2v q10 = *(const u2v*)(cells + c + 512);
            u2v q11 = *(const u2v*)(cells + c + 528);

            float az0 = 1.f - fz;
            float zz[4];
            unsigned los[4] = {q00.x, q01.x, q10.x, q11.x};
            unsigned his[4] = {q00.y, q01.y, q10.y, q11.y};
#pragma unroll
            for (int p2 = 0; p2 < 4; ++p2) {
                unsigned long long v = ((unsigned long long)his[p2] << 32) | los[p2];
                unsigned pr = (unsigned)(v >> sh);
                __half2 hp = *(__half2*)&pr;
                float2 f2 = __half22float2(hp);
                zz[p2] = az0 * f2.x + fz * f2.y;
            }
            float ay0 = 1.f - fy;
            acc = (1.f - fx) * (ay0 * zz[0] + fy * zz[1]) +
                  fx         * (ay0 * zz[2] + fy * zz[3]);
        } else {
            // rare (~0.1%): exact fp32 global gather with zero-padding.
            int x1 = x0 + 1, y1 = y0 + 1, z1 = z0 + 1;
            bool vx0 = (unsigned)x0 < (unsigned)H;
            bool vx1 = (unsigned)x1 < (unsigned)H;
            bool vy0 = (unsigned)y0 < (unsigned)W;
            bool vy1 = (unsigned)y1 < (unsigned)W;
            bool vz0 = (unsigned)z0 < (unsigned)D;
            bool vz1 = (unsigned)z1 < (unsigned)D;
            float ax0 = vx0 ? (1.0f - fx) : 0.0f;
            float ax1 = vx1 ? fx          : 0.0f;
            float ay0 = vy0 ? (1.0f - fy) : 0.0f;
            float ay1 = vy1 ? fy          : 0.0f;
            float az0 = vz0 ? (1.0f - fz) : 0.0f;
            float az1 = vz1 ? fz          : 0.0f;
            int cx0 = vx0 ? x0 : 0;
            int cx1 = vx1 ? x1 : 0;
            int cy0 = vy0 ? y0 : 0;
            int cy1 = vy1 ? y1 : 0;
            int cz0 = vz0 ? z0 : 0;
            int cz1 = vz1 ? z1 : 0;
            int rx0 = cx0 << 14, rx1 = cx1 << 14;
            int ry0 = cy0 << 7,  ry1 = cy1 << 7;
            float v000 = img[rx0 + ry0 + cz0];
            float v001 = img[rx0 + ry0 + cz1];
            float v010 = img[rx0 + ry1 + cz0];
            float v011 = img[rx0 + ry1 + cz1];
            float v100 = img[rx1 + ry0 + cz0];
            float v101 = img[rx1 + ry0 + cz1];
            float v110 = img[rx1 + ry1 + cz0];
            float v111 = img[rx1 + ry1 + cz1];
            acc = ax0 * (ay0 * (az0 * v000 + az1 * v001) +
                         ay1 * (az0 * v010 + az1 * v011)) +
                  ax1 * (ay0 * (az0 * v100 + az1 * v101) +
                         ay1 * (az0 * v110 + az1 * v111));
        }
        res[i] = acc;
    }
    fvec4 r4 = {res[0], res[1], res[2], res[3]};
    __builtin_nontemporal_store(r4, (fvec4*)(outb + lin0));
}

extern "C" void kernel_launch(void* const* d_in, const int* in_sizes, int n_in,
                              void* d_out, int out_size, void* d_ws, size_t ws_size,
                              hipStream_t stream) {
    const float* image = (const float*)d_in[0];
    const float* ddf   = (const float*)d_in[1];
    float* out = (float*)d_out;

    warp_tile_kernel<<<B * 512, 1024, 0, stream>>>(image, ddf, out);
}